// Round 8
// baseline (429.757 us; speedup 1.0000x reference)
//
#include <hip/hip_runtime.h>

typedef __bf16 bf16_t;
typedef __bf16 bf16x8 __attribute__((ext_vector_type(8)));
typedef float  f32x4  __attribute__((ext_vector_type(4)));
typedef float  f32x4u __attribute__((ext_vector_type(4), aligned(4)));

#define ASYNC16(g, l) __builtin_amdgcn_global_load_lds( \
    (const __attribute__((address_space(1))) void*)(g), \
    (__attribute__((address_space(3))) void*)(l), 16, 0, 0)

#define MFMA(a, b, c) __builtin_amdgcn_mfma_f32_16x16x32_bf16(a, b, c, 0, 0, 0)

// ---------------------------------------------------------------- cast all fp32 -> bf16
__global__ __launch_bounds__(256) void cast_all(
    const float* __restrict__ x, const float* __restrict__ wq,
    const float* __restrict__ wk, const float* __restrict__ wv,
    const float* __restrict__ wo,
    bf16_t* __restrict__ xb, bf16_t* __restrict__ wqkvb, bf16_t* __restrict__ wob)
{
  int i4 = blockIdx.x * 256 + threadIdx.x;
  int base = i4 * 4;
  const float* src; bf16_t* dst;
  if (base < 4194304) { src = x + base; dst = xb + base; }
  else {
    int j = base - 4194304;
    int w = j >> 20, o = j & 1048575;
    if      (w == 0) { src = wq + o; dst = wqkvb + o; }
    else if (w == 1) { src = wk + o; dst = wqkvb + (1 << 20) + o; }
    else if (w == 2) { src = wv + o; dst = wqkvb + (2 << 20) + o; }
    else             { src = wo + o; dst = wob + o; }
  }
  float4 v = *(const float4*)src;
  union { bf16_t h[4]; uint2 u; } pk;
  pk.h[0] = (bf16_t)v.x; pk.h[1] = (bf16_t)v.y;
  pk.h[2] = (bf16_t)v.z; pk.h[3] = (bf16_t)v.w;
  *(uint2*)dst = pk.u;
}

// ---------------------------------------------------------------- bias tables
__global__ void build_tbl(const float* __restrict__ rel_bias,
                          float* __restrict__ tblB, float* __restrict__ tblE)
{
  int i = blockIdx.x * 256 + threadIdx.x;
  if (i >= 4095 * 16) return;
  int rpi = i >> 4;
  int h = i & 15;
  int rp = rpi - 2047;
  int ret = rp >= 0 ? 16 : 0;
  int n = rp < 0 ? -rp : rp;
  int b;
  if (n < 8) b = ret + n;
  else {
    double v = 2.0 * (log2((double)n) - 3.0);   // log(n/8)/log(16)*8
    int bi = 8 + (int)v;
    b = ret + (bi < 15 ? bi : 15);
  }
  float v = rel_bias[b * 16 + h];
  tblB[h * 4096 + rpi] = v;
  tblE[h * 4096 + rpi] = v * 1.4426950408889634f;
}

// ---------------------------------------------------------------- QKV GEMM (128x128)
__global__ __launch_bounds__(256) void gemm_qkv(
    const bf16_t* __restrict__ A, const bf16_t* __restrict__ B,
    bf16_t* __restrict__ qk, bf16_t* __restrict__ vt)
{
  const int K = 1024;
  __shared__ bf16_t As[128 * 32];
  __shared__ bf16_t Bs[128 * 32];
  const int t = threadIdx.x;
  const int w = t >> 6, l = t & 63, ln = l & 15, quad = l >> 4;
  const int wm = (w & 1) * 64, wn = (w >> 1) * 64;
  const int m0 = blockIdx.x * 128, n0 = blockIdx.y * 128;

  f32x4 acc[4][4] = {};
  const int rA = t >> 2, c8 = (t & 3) * 8;
  const bf16_t* Ag = A + (size_t)(m0 + rA) * K + c8;
  const bf16_t* Bg = B + (size_t)(n0 + rA) * K + c8;
  const size_t K64 = (size_t)64 * K;
  bf16_t* As0 = &As[t * 8];  bf16_t* As1 = &As[2048 + t * 8];
  bf16_t* Bs0 = &Bs[t * 8];  bf16_t* Bs1 = &Bs[2048 + t * 8];

  for (int kt = 0; kt < K; kt += 32) {
    ASYNC16(Ag + kt,       As0);
    ASYNC16(Ag + kt + K64, As1);
    ASYNC16(Bg + kt,       Bs0);
    ASYNC16(Bg + kt + K64, Bs1);
    __syncthreads();
    bf16x8 a[4], b[4];
#pragma unroll
    for (int mi = 0; mi < 4; ++mi)
      a[mi] = *(const bf16x8*)&As[(wm + mi * 16 + ln) * 32 + quad * 8];
#pragma unroll
    for (int ni = 0; ni < 4; ++ni)
      b[ni] = *(const bf16x8*)&Bs[(wn + ni * 16 + ln) * 32 + quad * 8];
#pragma unroll
    for (int mi = 0; mi < 4; ++mi)
#pragma unroll
      for (int ni = 0; ni < 4; ++ni)
        acc[mi][ni] = MFMA(a[mi], b[ni], acc[mi][ni]);
    __syncthreads();
  }

  if (n0 >= 2048) {                       // V block -> transposed write
#pragma unroll
    for (int mi = 0; mi < 4; ++mi)
#pragma unroll
      for (int ni = 0; ni < 4; ++ni) {
        int col = n0 + wn + ni * 16 + ln - 2048;
        int hh = col >> 6, dd = col & 63;
        int row = m0 + wm + mi * 16 + quad * 4;
        int bb = row >> 11, ss = row & 2047;
        union { bf16_t h4[4]; uint2 u; } pk;
#pragma unroll
        for (int j = 0; j < 4; ++j) pk.h4[j] = (bf16_t)acc[mi][ni][j];
        *(uint2*)&vt[((size_t)(bb * 16 + hh) * 64 + dd) * 2048 + ss] = pk.u;
      }
  } else {
#pragma unroll
    for (int mi = 0; mi < 4; ++mi)
#pragma unroll
      for (int ni = 0; ni < 4; ++ni) {
        int row = m0 + wm + mi * 16 + quad * 4;
        int col = n0 + wn + ni * 16 + ln;
#pragma unroll
        for (int j = 0; j < 4; ++j)
          qk[(size_t)(row + j) * 2048 + col] = (bf16_t)acc[mi][ni][j];
      }
  }
}

// ---------------------------------------------------------------- out-proj GEMM (64x128, 2 blocks/CU)
__global__ __launch_bounds__(256) void gemm_wo(
    const bf16_t* __restrict__ A, const bf16_t* __restrict__ B,
    float* __restrict__ C)
{
  const int K = 1024, N = 1024;
  __shared__ bf16_t As[64 * 32];
  __shared__ bf16_t Bs[128 * 32];
  const int t = threadIdx.x;
  const int w = t >> 6, l = t & 63, ln = l & 15, quad = l >> 4;
  const int wm = (w & 1) * 32, wn = (w >> 1) * 64;
  const int m0 = blockIdx.x * 64, n0 = blockIdx.y * 128;

  f32x4 acc[2][4] = {};
  const int rr = t >> 2, c8 = (t & 3) * 8;
  const bf16_t* Ag = A + (size_t)(m0 + rr) * K + c8;
  const bf16_t* Bg = B + (size_t)(n0 + rr) * K + c8;
  const size_t K64 = (size_t)64 * K;
  bf16_t* As0 = &As[t * 8];
  bf16_t* Bs0 = &Bs[t * 8];  bf16_t* Bs1 = &Bs[2048 + t * 8];

  for (int kt = 0; kt < K; kt += 32) {
    ASYNC16(Ag + kt,       As0);
    ASYNC16(Bg + kt,       Bs0);
    ASYNC16(Bg + kt + K64, Bs1);
    __syncthreads();
    bf16x8 a[2], b[4];
#pragma unroll
    for (int mi = 0; mi < 2; ++mi)
      a[mi] = *(const bf16x8*)&As[(wm + mi * 16 + ln) * 32 + quad * 8];
#pragma unroll
    for (int ni = 0; ni < 4; ++ni)
      b[ni] = *(const bf16x8*)&Bs[(wn + ni * 16 + ln) * 32 + quad * 8];
#pragma unroll
    for (int mi = 0; mi < 2; ++mi)
#pragma unroll
      for (int ni = 0; ni < 4; ++ni)
        acc[mi][ni] = MFMA(a[mi], b[ni], acc[mi][ni]);
    __syncthreads();
  }

#pragma unroll
  for (int mi = 0; mi < 2; ++mi)
#pragma unroll
    for (int ni = 0; ni < 4; ++ni) {
      int row = m0 + wm + mi * 16 + quad * 4;
      int col = n0 + wn + ni * 16 + ln;
#pragma unroll
      for (int j = 0; j < 4; ++j)
        C[(size_t)(row + j) * N + col] = acc[mi][ni][j];
    }
}

// ---------------------------------------------------------------- flash attention + fused past_bias writer
// No-max softmax (scores bounded), unnormalized PV accumulate, epilogue row-sum.
// Each block also streams its 128q x 1024k half of past_bias (batch index picks
// the k-half; past_bias is batch-independent) overlapped with compute.
__global__ __launch_bounds__(512, 4) void flash_attn(
    const bf16_t* __restrict__ qk, const bf16_t* __restrict__ vt,
    const float* __restrict__ tblE, const float* __restrict__ tblB,
    bf16_t* __restrict__ attn, float* __restrict__ out1)
{
  __shared__ __align__(16) bf16_t Kt[128 * 64];   // [k][d], swz: pg = g ^ (row&7)
  __shared__ __align__(16) bf16_t Vs[64 * 128];   // [d][k], swz: pg = g ^ (row&15)
  __shared__ __align__(16) bf16_t Ps[8 * 16 * 128]; // per-wave [q][k], swz: pg = g ^ ln
  const int t = threadIdx.x, w = t >> 6, l = t & 63, ln = l & 15, quad = l >> 4;
  const int q0 = blockIdx.x * 128, h = blockIdx.y, b = blockIdx.z;
  const int S = 2048;
  const int q = q0 + w * 16 + ln;

  const bf16_t* Qp = qk + (size_t)(b * S + q) * 2048 + h * 64 + quad * 8;
  bf16x8 bq0 = *(const bf16x8*)Qp;
  bf16x8 bq1 = *(const bf16x8*)(Qp + 32);

  f32x4 o[4] = {};
  float li = 0.f;                                  // per-lane partial row sum

  const int krow = l >> 3;
  const int kg8  = ((l & 7) ^ krow) * 8;
  const int vrow = l >> 4;
  const int vg8  = ((l & 15) ^ ((w & 3) * 4 + vrow)) * 8;
  const bf16_t* Kg = qk + (size_t)(b * S) * 2048 + 1024 + h * 64 + kg8;
  const bf16_t* Vg = vt + (size_t)(b * 16 + h) * 64 * 2048 + vg8;
  const float* tb = tblE + h * 4096 + 2047 - q;

  // fused past_bias coords: this block covers rows [q0,q0+128) x k-half b
  const int bq = t >> 4;              // 0..31 (row within a 32-row group)
  const int bk = (t & 15) * 4;        // 0..60 (k within a 64-col chunk)
  const float* tbB = tblB + h * 4096 + 2047;
  float* o1 = out1 + ((size_t)h * 2048) * 2048 + b * 1024;

  for (int kt = 0; kt < S; kt += 128) {
    __syncthreads();
    ASYNC16(Kg + (size_t)(kt + w * 8 + krow) * 2048,      &Kt[(w * 8) * 64 + l * 8]);
    ASYNC16(Kg + (size_t)(kt + 64 + w * 8 + krow) * 2048, &Kt[(64 + w * 8) * 64 + l * 8]);
    ASYNC16(Vg + (size_t)(w * 4 + vrow) * 2048 + kt,      &Vs[(w * 4) * 128 + l * 8]);
    ASYNC16(Vg + (size_t)(32 + w * 4 + vrow) * 2048 + kt, &Vs[(32 + w * 4) * 128 + l * 8]);
    __syncthreads();

    // fused past_bias chunk: 128q x 64k per iter, drains by next-iter barrier
    {
      int kc = (kt >> 1) + bk;              // 0..1020 within this k-half
#pragma unroll
      for (int s = 0; s < 4; ++s) {
        int qr = q0 + s * 32 + bq;
        f32x4u v = *(const f32x4u*)(tbB + (b * 1024 + kc) - qr);
        *(f32x4*)&o1[(size_t)qr * 2048 + kc] = v;
      }
    }

    // S^T = K Q^T, exp fused per f-block, P -> wave-private LDS
    const float* tbk = tb + kt;
    bf16_t* pw = &Ps[w * 2048 + ln * 128];
#pragma unroll
    for (int f = 0; f < 8; ++f) {
      const bf16_t* kp = &Kt[(f * 16 + ln) * 64];
      bf16x8 a0 = *(const bf16x8*)(kp + ((quad ^ (ln & 7)) * 8));
      bf16x8 a1 = *(const bf16x8*)(kp + (((4 + quad) ^ (ln & 7)) * 8));
      f32x4 acc = {};
      acc = MFMA(a0, bq0, acc);
      acc = MFMA(a1, bq1, acc);
      f32x4u bv = *(const f32x4u*)(tbk + f * 16 + quad * 4);
      union { bf16_t h4[4]; uint2 u; } pk;
#pragma unroll
      for (int j = 0; j < 4; ++j) {
        float p = __builtin_amdgcn_exp2f(fmaf(acc[j], 0.18033688011112042f, bv[j]));
        li += p;
        pk.h4[j] = (bf16_t)p;
      }
      *(uint2*)&pw[(((2 * f + (quad >> 1)) ^ ln) * 8) + (quad & 1) * 4] = pk.u;
    }

    // O^T += V^T P^T (unnormalized)
#pragma unroll
    for (int kk = 0; kk < 4; ++kk) {
      bf16x8 bp = *(const bf16x8*)&Ps[w * 2048 + ln * 128 + (((kk * 4 + quad) ^ ln) * 8)];
#pragma unroll
      for (int dt = 0; dt < 4; ++dt) {
        bf16x8 av = *(const bf16x8*)&Vs[(dt * 16 + ln) * 128 + (((kk * 4 + quad) ^ ln) * 8)];
        o[dt] = MFMA(av, bp, o[dt]);
      }
    }
  }

  li += __shfl_xor(li, 16);
  li += __shfl_xor(li, 32);
  float inv = 1.f / li;
  bf16_t* op = attn + (size_t)(b * S + q) * 1024 + h * 64 + quad * 4;
#pragma unroll
  for (int dt = 0; dt < 4; ++dt) {
    union { bf16_t h4[4]; uint2 u; } pk;
#pragma unroll
    for (int j = 0; j < 4; ++j) pk.h4[j] = (bf16_t)(o[dt][j] * inv);
    *(uint2*)&op[dt * 16] = pk.u;
  }
}

// ---------------------------------------------------------------- launch
extern "C" void kernel_launch(void* const* d_in, const int* in_sizes, int n_in,
                              void* d_out, int out_size, void* d_ws, size_t ws_size,
                              hipStream_t stream)
{
  const float* x  = (const float*)d_in[0];
  const float* wq = (const float*)d_in[1];
  const float* wk = (const float*)d_in[2];
  const float* wv = (const float*)d_in[3];
  const float* wo = (const float*)d_in[4];
  const float* rb = (const float*)d_in[5];
  float* out0 = (float*)d_out;
  float* out1 = out0 + 4194304;

  char* ws = (char*)d_ws;
  bf16_t* xb    = (bf16_t*)(ws);                 // 8 MB (reused as attnb)
  bf16_t* wqkvb = (bf16_t*)(ws + 8388608);       // 6 MB
  bf16_t* wob   = (bf16_t*)(ws + 14680064);      // 2 MB
  bf16_t* qk    = (bf16_t*)(ws + 16777216);      // 16 MB
  bf16_t* vt    = (bf16_t*)(ws + 33554432);      // 8 MB
  float*  tblB  = (float*)(ws + 41943040);       // 256 KB
  float*  tblE  = (float*)(ws + 42205184);       // 256 KB
  bf16_t* attnb = xb;

  cast_all<<<8192, 256, 0, stream>>>(x, wq, wk, wv, wo, xb, wqkvb, wob);
  build_tbl<<<256, 256, 0, stream>>>(rb, tblB, tblE);
  gemm_qkv<<<dim3(32, 24), 256, 0, stream>>>(xb, wqkvb, qk, vt);
  flash_attn<<<dim3(16, 16, 2), 512, 0, stream>>>(qk, vt, tblE, tblB, attnb, out1);
  gemm_wo<<<dim3(64, 8), 256, 0, stream>>>(attnb, wob, out0);
}

// Round 9
// 408.872 us; speedup vs baseline: 1.0511x; 1.0511x over previous
//
#include <hip/hip_runtime.h>

typedef __bf16 bf16_t;
typedef __bf16 bf16x8 __attribute__((ext_vector_type(8)));
typedef float  f32x4  __attribute__((ext_vector_type(4)));
typedef float  f32x4u __attribute__((ext_vector_type(4), aligned(4)));

#define ASYNC16(g, l) __builtin_amdgcn_global_load_lds( \
    (const __attribute__((address_space(1))) void*)(g), \
    (__attribute__((address_space(3))) void*)(l), 16, 0, 0)

#define MFMA(a, b, c) __builtin_amdgcn_mfma_f32_16x16x32_bf16(a, b, c, 0, 0, 0)

// ---------------------------------------------------------------- cast all fp32 -> bf16
__global__ __launch_bounds__(256) void cast_all(
    const float* __restrict__ x, const float* __restrict__ wq,
    const float* __restrict__ wk, const float* __restrict__ wv,
    const float* __restrict__ wo,
    bf16_t* __restrict__ xb, bf16_t* __restrict__ wqkvb, bf16_t* __restrict__ wob)
{
  int i4 = blockIdx.x * 256 + threadIdx.x;
  int base = i4 * 4;
  const float* src; bf16_t* dst;
  if (base < 4194304) { src = x + base; dst = xb + base; }
  else {
    int j = base - 4194304;
    int w = j >> 20, o = j & 1048575;
    if      (w == 0) { src = wq + o; dst = wqkvb + o; }
    else if (w == 1) { src = wk + o; dst = wqkvb + (1 << 20) + o; }
    else if (w == 2) { src = wv + o; dst = wqkvb + (2 << 20) + o; }
    else             { src = wo + o; dst = wob + o; }
  }
  float4 v = *(const float4*)src;
  union { bf16_t h[4]; uint2 u; } pk;
  pk.h[0] = (bf16_t)v.x; pk.h[1] = (bf16_t)v.y;
  pk.h[2] = (bf16_t)v.z; pk.h[3] = (bf16_t)v.w;
  *(uint2*)dst = pk.u;
}

// ---------------------------------------------------------------- bias tables
__global__ void build_tbl(const float* __restrict__ rel_bias,
                          float* __restrict__ tblB, float* __restrict__ tblE)
{
  int i = blockIdx.x * 256 + threadIdx.x;
  if (i >= 4095 * 16) return;
  int rpi = i >> 4;
  int h = i & 15;
  int rp = rpi - 2047;
  int ret = rp >= 0 ? 16 : 0;
  int n = rp < 0 ? -rp : rp;
  int b;
  if (n < 8) b = ret + n;
  else {
    double v = 2.0 * (log2((double)n) - 3.0);   // log(n/8)/log(16)*8
    int bi = 8 + (int)v;
    b = ret + (bi < 15 ? bi : 15);
  }
  float v = rel_bias[b * 16 + h];
  tblB[h * 4096 + rpi] = v;
  tblE[h * 4096 + rpi] = v * 1.4426950408889634f;
}

// ---------------------------------------------------------------- QKV GEMM (128x128)
__global__ __launch_bounds__(256) void gemm_qkv(
    const bf16_t* __restrict__ A, const bf16_t* __restrict__ B,
    bf16_t* __restrict__ qk, bf16_t* __restrict__ vt)
{
  const int K = 1024;
  __shared__ bf16_t As[128 * 32];
  __shared__ bf16_t Bs[128 * 32];
  const int t = threadIdx.x;
  const int w = t >> 6, l = t & 63, ln = l & 15, quad = l >> 4;
  const int wm = (w & 1) * 64, wn = (w >> 1) * 64;
  const int m0 = blockIdx.x * 128, n0 = blockIdx.y * 128;

  f32x4 acc[4][4] = {};
  const int rA = t >> 2, c8 = (t & 3) * 8;
  const bf16_t* Ag = A + (size_t)(m0 + rA) * K + c8;
  const bf16_t* Bg = B + (size_t)(n0 + rA) * K + c8;
  const size_t K64 = (size_t)64 * K;
  bf16_t* As0 = &As[t * 8];  bf16_t* As1 = &As[2048 + t * 8];
  bf16_t* Bs0 = &Bs[t * 8];  bf16_t* Bs1 = &Bs[2048 + t * 8];

  for (int kt = 0; kt < K; kt += 32) {
    ASYNC16(Ag + kt,       As0);
    ASYNC16(Ag + kt + K64, As1);
    ASYNC16(Bg + kt,       Bs0);
    ASYNC16(Bg + kt + K64, Bs1);
    __syncthreads();
    bf16x8 a[4], b[4];
#pragma unroll
    for (int mi = 0; mi < 4; ++mi)
      a[mi] = *(const bf16x8*)&As[(wm + mi * 16 + ln) * 32 + quad * 8];
#pragma unroll
    for (int ni = 0; ni < 4; ++ni)
      b[ni] = *(const bf16x8*)&Bs[(wn + ni * 16 + ln) * 32 + quad * 8];
#pragma unroll
    for (int mi = 0; mi < 4; ++mi)
#pragma unroll
      for (int ni = 0; ni < 4; ++ni)
        acc[mi][ni] = MFMA(a[mi], b[ni], acc[mi][ni]);
    __syncthreads();
  }

  if (n0 >= 2048) {                       // V block -> transposed write
#pragma unroll
    for (int mi = 0; mi < 4; ++mi)
#pragma unroll
      for (int ni = 0; ni < 4; ++ni) {
        int col = n0 + wn + ni * 16 + ln - 2048;
        int hh = col >> 6, dd = col & 63;
        int row = m0 + wm + mi * 16 + quad * 4;
        int bb = row >> 11, ss = row & 2047;
        union { bf16_t h4[4]; uint2 u; } pk;
#pragma unroll
        for (int j = 0; j < 4; ++j) pk.h4[j] = (bf16_t)acc[mi][ni][j];
        *(uint2*)&vt[((size_t)(bb * 16 + hh) * 64 + dd) * 2048 + ss] = pk.u;
      }
  } else {
#pragma unroll
    for (int mi = 0; mi < 4; ++mi)
#pragma unroll
      for (int ni = 0; ni < 4; ++ni) {
        int row = m0 + wm + mi * 16 + quad * 4;
        int col = n0 + wn + ni * 16 + ln;
#pragma unroll
        for (int j = 0; j < 4; ++j)
          qk[(size_t)(row + j) * 2048 + col] = (bf16_t)acc[mi][ni][j];
      }
  }
}

// ---------------------------------------------------------------- out-proj GEMM (64x128, 2 blocks/CU)
__global__ __launch_bounds__(256) void gemm_wo(
    const bf16_t* __restrict__ A, const bf16_t* __restrict__ B,
    float* __restrict__ C)
{
  const int K = 1024, N = 1024;
  __shared__ bf16_t As[64 * 32];
  __shared__ bf16_t Bs[128 * 32];
  const int t = threadIdx.x;
  const int w = t >> 6, l = t & 63, ln = l & 15, quad = l >> 4;
  const int wm = (w & 1) * 32, wn = (w >> 1) * 64;
  const int m0 = blockIdx.x * 64, n0 = blockIdx.y * 128;

  f32x4 acc[2][4] = {};
  const int rr = t >> 2, c8 = (t & 3) * 8;
  const bf16_t* Ag = A + (size_t)(m0 + rr) * K + c8;
  const bf16_t* Bg = B + (size_t)(n0 + rr) * K + c8;
  const size_t K64 = (size_t)64 * K;
  bf16_t* As0 = &As[t * 8];
  bf16_t* Bs0 = &Bs[t * 8];  bf16_t* Bs1 = &Bs[2048 + t * 8];

  for (int kt = 0; kt < K; kt += 32) {
    ASYNC16(Ag + kt,       As0);
    ASYNC16(Bg + kt,       Bs0);
    ASYNC16(Bg + kt + K64, Bs1);
    __syncthreads();
    bf16x8 a[2], b[4];
#pragma unroll
    for (int mi = 0; mi < 2; ++mi)
      a[mi] = *(const bf16x8*)&As[(wm + mi * 16 + ln) * 32 + quad * 8];
#pragma unroll
    for (int ni = 0; ni < 4; ++ni)
      b[ni] = *(const bf16x8*)&Bs[(wn + ni * 16 + ln) * 32 + quad * 8];
#pragma unroll
    for (int mi = 0; mi < 2; ++mi)
#pragma unroll
      for (int ni = 0; ni < 4; ++ni)
        acc[mi][ni] = MFMA(a[mi], b[ni], acc[mi][ni]);
    __syncthreads();
  }

#pragma unroll
  for (int mi = 0; mi < 2; ++mi)
#pragma unroll
    for (int ni = 0; ni < 4; ++ni) {
      int row = m0 + wm + mi * 16 + quad * 4;
      int col = n0 + wn + ni * 16 + ln;
#pragma unroll
      for (int j = 0; j < 4; ++j)
        C[(size_t)(row + j) * N + col] = acc[mi][ni][j];
    }
}

// ---------------------------------------------------------------- flash attention
// 32 q-rows per wave (two 16-row B-frags) -> each K/V LDS read serves 2x q-rows,
// halving LDS read traffic. 4 waves/block, 128-q tile, K-tile 128, no-max softmax.
// LDS = Kt 16K + Vs 16K + Ps 32K = 64 KB -> 2 blocks/CU.
__global__ __launch_bounds__(256, 2) void flash_attn(
    const bf16_t* __restrict__ qk, const bf16_t* __restrict__ vt,
    const float* __restrict__ tblE, bf16_t* __restrict__ attn)
{
  __shared__ __align__(16) bf16_t Kt[128 * 64];   // [k][d], swz: pg = g ^ (row&7)
  __shared__ __align__(16) bf16_t Vs[64 * 128];   // [d][k], swz: pg = g ^ (row&15)
  __shared__ __align__(16) bf16_t Ps[4 * 32 * 128]; // per-wave [q32][k], swz: pg = g ^ (q&15)
  const int t = threadIdx.x, w = t >> 6, l = t & 63, ln = l & 15, quad = l >> 4;
  const int q0 = blockIdx.x * 128, h = blockIdx.y, b = blockIdx.z;
  const int S = 2048;
  const int qa = q0 + w * 32 + ln;      // frag-a q row
  const int qb = qa + 16;               // frag-b q row

  const bf16_t* Qpa = qk + (size_t)(b * S + qa) * 2048 + h * 64 + quad * 8;
  const bf16_t* Qpb = qk + (size_t)(b * S + qb) * 2048 + h * 64 + quad * 8;
  bf16x8 bq0a = *(const bf16x8*)Qpa;
  bf16x8 bq1a = *(const bf16x8*)(Qpa + 32);
  bf16x8 bq0b = *(const bf16x8*)Qpb;
  bf16x8 bq1b = *(const bf16x8*)(Qpb + 32);

  f32x4 oa[4] = {}, ob[4] = {};
  float lia = 0.f, lib = 0.f;

  const int krow = l >> 3;
  const int kg8  = ((l & 7) ^ krow) * 8;
  const int vrow = l >> 4;
  const int vg8  = ((l & 15) ^ (w * 4 + vrow)) * 8;   // row&15 = w*4+vrow (w<4)
  const bf16_t* Kg = qk + (size_t)(b * S) * 2048 + 1024 + h * 64 + kg8;
  const bf16_t* Vg = vt + (size_t)(b * 16 + h) * 64 * 2048 + vg8;
  const float* tba = tblE + h * 4096 + 2047 - qa;
  const float* tbb = tblE + h * 4096 + 2047 - qb;

  for (int kt = 0; kt < S; kt += 128) {
    __syncthreads();
    // K: 4 waves x 8 rows x 4 rounds = 128 rows; V: 4 waves x 4 rows x 4 rounds = 64
#pragma unroll
    for (int cc = 0; cc < 4; ++cc) {
      int kr0 = w * 8 + cc * 32;
      ASYNC16(Kg + (size_t)(kt + kr0 + krow) * 2048, &Kt[kr0 * 64 + l * 8]);
      int vr0 = w * 4 + cc * 16;
      ASYNC16(Vg + (size_t)(vr0 + vrow) * 2048 + kt, &Vs[vr0 * 128 + l * 8]);
    }
    __syncthreads();

    // S^T = K Q^T for both q-frags; exp fused; P -> wave-private LDS
    const float* tbka = tba + kt;
    const float* tbkb = tbb + kt;
    bf16_t* pwa = &Ps[w * 4096 + ln * 128];
    bf16_t* pwb = pwa + 16 * 128;
#pragma unroll
    for (int f = 0; f < 8; ++f) {
      const bf16_t* kp = &Kt[(f * 16 + ln) * 64];
      bf16x8 a0 = *(const bf16x8*)(kp + ((quad ^ (ln & 7)) * 8));
      bf16x8 a1 = *(const bf16x8*)(kp + (((4 + quad) ^ (ln & 7)) * 8));
      f32x4 acca = {}, accb = {};
      acca = MFMA(a0, bq0a, acca);
      acca = MFMA(a1, bq1a, acca);
      accb = MFMA(a0, bq0b, accb);
      accb = MFMA(a1, bq1b, accb);
      f32x4u bva = *(const f32x4u*)(tbka + f * 16 + quad * 4);
      f32x4u bvb = *(const f32x4u*)(tbkb + f * 16 + quad * 4);
      union { bf16_t h4[4]; uint2 u; } pka, pkb;
#pragma unroll
      for (int j = 0; j < 4; ++j) {
        float pa = __builtin_amdgcn_exp2f(fmaf(acca[j], 0.18033688011112042f, bva[j]));
        float pb = __builtin_amdgcn_exp2f(fmaf(accb[j], 0.18033688011112042f, bvb[j]));
        lia += pa; lib += pb;
        pka.h4[j] = (bf16_t)pa; pkb.h4[j] = (bf16_t)pb;
      }
      int po = (((2 * f + (quad >> 1)) ^ ln) * 8) + (quad & 1) * 4;
      *(uint2*)&pwa[po] = pka.u;
      *(uint2*)&pwb[po] = pkb.u;
    }

    // O^T += V^T P^T for both q-frags (V frags read once, used twice)
#pragma unroll
    for (int kk = 0; kk < 4; ++kk) {
      int so = ((kk * 4 + quad) ^ ln) * 8;
      bf16x8 bpa = *(const bf16x8*)&pwa[so];
      bf16x8 bpb = *(const bf16x8*)&pwb[so];
#pragma unroll
      for (int dt = 0; dt < 4; ++dt) {
        bf16x8 av = *(const bf16x8*)&Vs[(dt * 16 + ln) * 128 + so];
        oa[dt] = MFMA(av, bpa, oa[dt]);
        ob[dt] = MFMA(av, bpb, ob[dt]);
      }
    }
  }

  lia += __shfl_xor(lia, 16);
  lia += __shfl_xor(lia, 32);
  lib += __shfl_xor(lib, 16);
  lib += __shfl_xor(lib, 32);
  float inva = 1.f / lia, invb = 1.f / lib;
  bf16_t* opa = attn + (size_t)(b * S + qa) * 1024 + h * 64 + quad * 4;
  bf16_t* opb = attn + (size_t)(b * S + qb) * 1024 + h * 64 + quad * 4;
#pragma unroll
  for (int dt = 0; dt < 4; ++dt) {
    union { bf16_t h4[4]; uint2 u; } pka, pkb;
#pragma unroll
    for (int j = 0; j < 4; ++j) {
      pka.h4[j] = (bf16_t)(oa[dt][j] * inva);
      pkb.h4[j] = (bf16_t)(ob[dt][j] * invb);
    }
    *(uint2*)&opa[dt * 16] = pka.u;
    *(uint2*)&opb[dt * 16] = pkb.u;
  }
}

// ---------------------------------------------------------------- past_bias writer
__global__ __launch_bounds__(256) void bias_out(const float* __restrict__ tbl,
                                                float* __restrict__ out1)
{
  int i = blockIdx.x * 256 + threadIdx.x;
  int hq = i >> 9;
  int k4 = (i & 511) * 4;
  int h = hq >> 11, q = hq & 2047;
  const float* tp = tbl + (h << 12) + (k4 - q + 2047);
  float4 v;
  v.x = __ldg(tp);     v.y = __ldg(tp + 1);
  v.z = __ldg(tp + 2); v.w = __ldg(tp + 3);
  ((float4*)out1)[i] = v;
}

// ---------------------------------------------------------------- launch
extern "C" void kernel_launch(void* const* d_in, const int* in_sizes, int n_in,
                              void* d_out, int out_size, void* d_ws, size_t ws_size,
                              hipStream_t stream)
{
  const float* x  = (const float*)d_in[0];
  const float* wq = (const float*)d_in[1];
  const float* wk = (const float*)d_in[2];
  const float* wv = (const float*)d_in[3];
  const float* wo = (const float*)d_in[4];
  const float* rb = (const float*)d_in[5];
  float* out0 = (float*)d_out;
  float* out1 = out0 + 4194304;

  char* ws = (char*)d_ws;
  bf16_t* xb    = (bf16_t*)(ws);                 // 8 MB (reused as attnb)
  bf16_t* wqkvb = (bf16_t*)(ws + 8388608);       // 6 MB
  bf16_t* wob   = (bf16_t*)(ws + 14680064);      // 2 MB
  bf16_t* qk    = (bf16_t*)(ws + 16777216);      // 16 MB
  bf16_t* vt    = (bf16_t*)(ws + 33554432);      // 8 MB
  float*  tblB  = (float*)(ws + 41943040);       // 256 KB
  float*  tblE  = (float*)(ws + 42205184);       // 256 KB
  bf16_t* attnb = xb;

  cast_all<<<8192, 256, 0, stream>>>(x, wq, wk, wv, wo, xb, wqkvb, wob);
  build_tbl<<<256, 256, 0, stream>>>(rb, tblB, tblE);
  gemm_qkv<<<dim3(32, 24), 256, 0, stream>>>(xb, wqkvb, qk, vt);
  flash_attn<<<dim3(16, 16, 2), 256, 0, stream>>>(qk, vt, tblE, attnb);
  gemm_wo<<<dim3(64, 8), 256, 0, stream>>>(attnb, wob, out0);
  bias_out<<<65536, 256, 0, stream>>>(tblB, out1);
}